// Round 2
// baseline (576.802 us; speedup 1.0000x reference)
//
#include <hip/hip_runtime.h>

// MultiHeadAttention (B=2, L=2048, C=256, H=W=4, NH=8, DH=32)
// R2: all GEMMs use global_load_lds width-16 async staging (m97 structure);
//     gemm_ctx converts fp32 attn -> bf16 with v_cvt_pk_bf16_f32.
//
// Workspace layout (shorts): X 16.7M | q_s | k_s | v_s | Wbf  = 134.6 MB.

typedef short s16x8 __attribute__((ext_vector_type(8)));
typedef float f32x4 __attribute__((ext_vector_type(4)));

__device__ __forceinline__ unsigned short f2bf(float f) {
  union { float f; unsigned int u; } v; v.f = f;
  return (unsigned short)((v.u + 0x7FFFu + ((v.u >> 16) & 1u)) >> 16);  // RNE
}

__device__ __forceinline__ unsigned cvt_pk_bf16(float a, float b) {
  unsigned r;
  asm volatile("v_cvt_pk_bf16_f32 %0, %1, %2" : "=v"(r) : "v"(a), "v"(b));
  return r;  // lo = bf16(a), hi = bf16(b)
}

// async global->LDS, 16B per lane; lds base must be wave-uniform (HW adds lane*16)
__device__ __forceinline__ void async_copy16(const unsigned short* g, unsigned short* l) {
  __builtin_amdgcn_global_load_lds((const __attribute__((address_space(1))) void*)g,
                                   (__attribute__((address_space(3))) void*)l, 16, 0, 0);
}

// ---------------- prep: (B,L,C,H,W) fp32 -> X[(b,l,hw)][c] bf16 ----------------
__global__ void __launch_bounds__(256) prep_x_kernel(const float* __restrict__ src,
                                                     unsigned short* __restrict__ dst) {
  __shared__ float ld[256 * 17];
  const int bl = blockIdx.x;
  const int t = threadIdx.x;
  const float* s = src + (size_t)bl * 4096;
#pragma unroll
  for (int i = 0; i < 4; ++i) {
    int flat = i * 1024 + t * 4;
    float4 v = *(const float4*)(s + flat);
    int c = flat >> 4, hw = flat & 15;
    float* p = &ld[c * 17 + hw];
    p[0] = v.x; p[1] = v.y; p[2] = v.z; p[3] = v.w;
  }
  __syncthreads();
  unsigned short* d = dst + (size_t)bl * 4096;
#pragma unroll
  for (int hw = 0; hw < 16; ++hw)
    d[hw * 256 + t] = f2bf(ld[t * 17 + hw]);
}

__global__ void __launch_bounds__(256) prep_w_kernel(const float* __restrict__ a,
                                                     const float* __restrict__ b,
                                                     const float* __restrict__ c,
                                                     unsigned short* __restrict__ dst) {
  int i = blockIdx.x * 256 + threadIdx.x;
  const float* s = (i < 65536) ? a : ((i < 131072) ? b : c);
  dst[i] = f2bf(s[i & 65535]);
}

// ---------------- shared async GEMM core: C(128x128) += A(128xK) * Bt(128xK)^T ----------------
// A,B row-major k-contiguous bf16. LDS tiles [128][32] linear.
__device__ __forceinline__ void gemm_core_async(const unsigned short* __restrict__ Ag, int ldA,
                                                const unsigned short* __restrict__ Bg, int ldB,
                                                int K, unsigned short* As, unsigned short* Bs,
                                                f32x4 acc[4][4]) {
  const int tid = threadIdx.x;
  const int lane = tid & 63;
  const int w = tid >> 6;
  const int wr = (w >> 1) * 64, wc = (w & 1) * 64;
  const int r = lane >> 2, kk = (lane & 3) * 8;   // stage: 4 lanes/row, 8 shorts each
  for (int k0 = 0; k0 < K; k0 += 32) {
#pragma unroll
    for (int i = 0; i < 2; ++i) {
      const int row0 = w * 32 + i * 16;           // wave stages rows [w*32, w*32+32)
      async_copy16(Ag + (size_t)(row0 + r) * ldA + k0 + kk, As + row0 * 32);
      async_copy16(Bg + (size_t)(row0 + r) * ldB + k0 + kk, Bs + row0 * 32);
    }
    __syncthreads();
    s16x8 af[4], bfv[4];
#pragma unroll
    for (int m = 0; m < 4; ++m)
      af[m] = *(const s16x8*)(As + (wr + m * 16 + (lane & 15)) * 32 + (lane >> 4) * 8);
#pragma unroll
    for (int n = 0; n < 4; ++n)
      bfv[n] = *(const s16x8*)(Bs + (wc + n * 16 + (lane & 15)) * 32 + (lane >> 4) * 8);
#pragma unroll
    for (int m = 0; m < 4; ++m)
#pragma unroll
      for (int n = 0; n < 4; ++n)
        acc[m][n] = __builtin_amdgcn_mfma_f32_16x16x32_bf16(af[m], bfv[n], acc[m][n], 0, 0, 0);
    __syncthreads();
  }
}

#define ACC_INIT(acc)                         \
  {                                           \
    const f32x4 z_ = {0.f, 0.f, 0.f, 0.f};    \
    _Pragma("unroll")                         \
    for (int m_ = 0; m_ < 4; ++m_)            \
      _Pragma("unroll")                       \
      for (int n_ = 0; n_ < 4; ++n_) acc[m_][n_] = z_; \
  }

// ---------------- projection: X(65536x256) * W(256x256)^T -> q_s[bh][l][512] bf16 ----------------
__global__ void __launch_bounds__(256) gemm_proj_kernel(const unsigned short* __restrict__ X,
                                                        const unsigned short* __restrict__ W,
                                                        unsigned short* __restrict__ out) {
  __shared__ unsigned short As[4096], Bs[4096];
  f32x4 acc[4][4];
  ACC_INIT(acc);
  gemm_core_async(X + (size_t)blockIdx.x * 128 * 256, 256,
                  W + (size_t)blockIdx.y * 128 * 256, 256, 256, As, Bs, acc);
  const int tid = threadIdx.x, lane = tid & 63, w = tid >> 6;
  const int wr = (w >> 1) * 64, wc = (w & 1) * 64;
  const int R0 = blockIdx.x * 128 + wr + ((lane >> 4) << 2);
  const int C0 = blockIdx.y * 128 + wc + (lane & 15);
#pragma unroll
  for (int m = 0; m < 4; ++m)
#pragma unroll
    for (int n = 0; n < 4; ++n)
#pragma unroll
      for (int r = 0; r < 4; ++r) {
        int R = R0 + m * 16 + r;          // p = (b*L + l)*16 + hw
        int o = C0 + n * 16;
        int bl = R >> 4, hw = R & 15;
        int b = bl >> 11, l = bl & 2047;
        int head = o >> 5, d = o & 31;
        out[((size_t)(head * 2 + b) * 2048 + l) * 512 + d * 16 + hw] = f2bf(acc[m][n][r]);
      }
}

// ---------------- score: q_s[bh] (2048x512) * k_s[bh]^T -> attn (raw, scaled) fp32 ----------------
__global__ void __launch_bounds__(256) gemm_score_kernel(const unsigned short* __restrict__ q,
                                                         const unsigned short* __restrict__ k,
                                                         float* __restrict__ attn) {
  __shared__ unsigned short As[4096], Bs[4096];
  f32x4 acc[4][4];
  ACC_INIT(acc);
  const int bh = blockIdx.z;
  gemm_core_async(q + ((size_t)bh * 2048 + blockIdx.x * 128) * 512, 512,
                  k + ((size_t)bh * 2048 + blockIdx.y * 128) * 512, 512, 512, As, Bs, acc);
  const int tid = threadIdx.x, lane = tid & 63, w = tid >> 6;
  const int wr = (w >> 1) * 64, wc = (w & 1) * 64;
  float* O = attn + (size_t)bh * 2048 * 2048;
  const float scale = 0.17677669529663687f;  // 1/sqrt(32)
  const int R0 = blockIdx.x * 128 + wr + ((lane >> 4) << 2);
  const int C0 = blockIdx.y * 128 + wc + (lane & 15);
#pragma unroll
  for (int m = 0; m < 4; ++m)
#pragma unroll
    for (int n = 0; n < 4; ++n)
#pragma unroll
      for (int r = 0; r < 4; ++r)
        O[(size_t)(R0 + m * 16 + r) * 2048 + (C0 + n * 16)] = acc[m][n][r] * scale;
}

// ---------------- softmax over rows of attn (in place) ----------------
__global__ void __launch_bounds__(256) softmax_kernel(float* __restrict__ attn) {
  __shared__ float red[4];
  float* p = attn + (size_t)blockIdx.x * 2048;
  const int t = threadIdx.x;
  float4 v0 = *(const float4*)(p + t * 8);
  float4 v1 = *(const float4*)(p + t * 8 + 4);
  float mx = fmaxf(fmaxf(fmaxf(v0.x, v0.y), fmaxf(v0.z, v0.w)),
                   fmaxf(fmaxf(v1.x, v1.y), fmaxf(v1.z, v1.w)));
#pragma unroll
  for (int off = 32; off; off >>= 1) mx = fmaxf(mx, __shfl_xor(mx, off));
  if ((t & 63) == 0) red[t >> 6] = mx;
  __syncthreads();
  mx = fmaxf(fmaxf(red[0], red[1]), fmaxf(red[2], red[3]));
  __syncthreads();
  float e[8];
  e[0] = __expf(v0.x - mx); e[1] = __expf(v0.y - mx);
  e[2] = __expf(v0.z - mx); e[3] = __expf(v0.w - mx);
  e[4] = __expf(v1.x - mx); e[5] = __expf(v1.y - mx);
  e[6] = __expf(v1.z - mx); e[7] = __expf(v1.w - mx);
  float s = ((e[0] + e[1]) + (e[2] + e[3])) + ((e[4] + e[5]) + (e[6] + e[7]));
#pragma unroll
  for (int off = 32; off; off >>= 1) s += __shfl_xor(s, off);
  if ((t & 63) == 0) red[t >> 6] = s;
  __syncthreads();
  s = red[0] + red[1] + red[2] + red[3];
  const float inv = 1.0f / s;
  float4 o0 = {e[0] * inv, e[1] * inv, e[2] * inv, e[3] * inv};
  float4 o1 = {e[4] * inv, e[5] * inv, e[6] * inv, e[7] * inv};
  *(float4*)(p + t * 8) = o0;
  *(float4*)(p + t * 8 + 4) = o1;
}

// ---------------- v_s[bh][j][dd] -> v_t[bh][dd][j] (bf16 transpose) ----------------
__global__ void __launch_bounds__(256) transpose_v_kernel(const unsigned short* __restrict__ vs,
                                                          unsigned short* __restrict__ vt) {
  __shared__ unsigned short tile[64][65];
  const int bh = blockIdx.z;
  const int j0 = blockIdx.x * 64, d0 = blockIdx.y * 64;
  const unsigned short* src = vs + (size_t)bh * 2048 * 512;
  unsigned short* dst = vt + (size_t)bh * 512 * 2048;
  const int t = threadIdx.x;
#pragma unroll
  for (int i = 0; i < 16; ++i) {
    int e = t * 16 + i;
    int r = e >> 6, c = e & 63;
    tile[r][c] = src[(size_t)(j0 + r) * 512 + d0 + c];
  }
  __syncthreads();
#pragma unroll
  for (int i = 0; i < 16; ++i) {
    int e = t * 16 + i;
    int r = e >> 6, c = e & 63;
    dst[(size_t)(d0 + r) * 2048 + j0 + c] = tile[c][r];
  }
}

// ---------------- context: attn(fp32, 2048x2048) * v_t^T -> out (B,L,C,H,W) fp32 ----------------
__global__ void __launch_bounds__(256) gemm_ctx_kernel(const float* __restrict__ attn,
                                                       const unsigned short* __restrict__ vt,
                                                       float* __restrict__ outc) {
  __shared__ unsigned short As[4096], Bs[4096];
  f32x4 acc[4][4];
  ACC_INIT(acc);
  const int tid = threadIdx.x, lane = tid & 63, w = tid >> 6;
  const int wr = (w >> 1) * 64, wc = (w & 1) * 64;
  const int bh = blockIdx.z;
  const float* Ag = attn + (size_t)bh * 4194304 + (size_t)blockIdx.x * 128 * 2048;
  const unsigned short* Bg = vt + (size_t)bh * 1048576 + (size_t)blockIdx.y * 128 * 2048;
  const int r = lane >> 2, kk = (lane & 3) * 8;   // B stage mapping
  const int arow = tid >> 1, acol = (tid & 1) * 16;  // A stage: 16 fp32 per thread
  for (int k0 = 0; k0 < 2048; k0 += 32) {
#pragma unroll
    for (int i = 0; i < 2; ++i) {
      const int row0 = w * 32 + i * 16;
      async_copy16(Bg + (size_t)(row0 + r) * 2048 + k0 + kk, Bs + row0 * 32);
    }
    {  // A stage: fp32 -> bf16 via v_cvt_pk_bf16_f32
      const float* sp = Ag + (size_t)arow * 2048 + k0 + acol;
      float4 f0 = *(const float4*)(sp);
      float4 f1 = *(const float4*)(sp + 4);
      float4 f2 = *(const float4*)(sp + 8);
      float4 f3 = *(const float4*)(sp + 12);
      union { s16x8 v; unsigned u[4]; } h0, h1;
      h0.u[0] = cvt_pk_bf16(f0.x, f0.y);
      h0.u[1] = cvt_pk_bf16(f0.z, f0.w);
      h0.u[2] = cvt_pk_bf16(f1.x, f1.y);
      h0.u[3] = cvt_pk_bf16(f1.z, f1.w);
      h1.u[0] = cvt_pk_bf16(f2.x, f2.y);
      h1.u[1] = cvt_pk_bf16(f2.z, f2.w);
      h1.u[2] = cvt_pk_bf16(f3.x, f3.y);
      h1.u[3] = cvt_pk_bf16(f3.z, f3.w);
      *(s16x8*)(As + arow * 32 + acol) = h0.v;
      *(s16x8*)(As + arow * 32 + acol + 8) = h1.v;
    }
    __syncthreads();
    s16x8 af[4], bfv[4];
#pragma unroll
    for (int m = 0; m < 4; ++m)
      af[m] = *(const s16x8*)(As + (wr + m * 16 + (lane & 15)) * 32 + (lane >> 4) * 8);
#pragma unroll
    for (int n = 0; n < 4; ++n)
      bfv[n] = *(const s16x8*)(Bs + (wc + n * 16 + (lane & 15)) * 32 + (lane >> 4) * 8);
#pragma unroll
    for (int m = 0; m < 4; ++m)
#pragma unroll
      for (int n = 0; n < 4; ++n)
        acc[m][n] = __builtin_amdgcn_mfma_f32_16x16x32_bf16(af[m], bfv[n], acc[m][n], 0, 0, 0);
    __syncthreads();
  }
  const int b = bh & 1, head = bh >> 1;
  const int R0 = blockIdx.x * 128 + wr + ((lane >> 4) << 2);
  const int C0 = blockIdx.y * 128 + wc + (lane & 15);
#pragma unroll
  for (int m = 0; m < 4; ++m)
#pragma unroll
    for (int n = 0; n < 4; ++n)
#pragma unroll
      for (int r2 = 0; r2 < 4; ++r2) {
        int R = R0 + m * 16 + r2;
        int dd = C0 + n * 16;
        int d = dd >> 4, hw = dd & 15;
        outc[((size_t)(b * 2048 + R) * 256 + head * 32 + d) * 16 + hw] = acc[m][n][r2];
      }
}

extern "C" void kernel_launch(void* const* d_in, const int* in_sizes, int n_in,
                              void* d_out, int out_size, void* d_ws, size_t ws_size,
                              hipStream_t stream) {
  const float* query = (const float*)d_in[0];
  const float* key   = (const float*)d_in[1];
  const float* value = (const float*)d_in[2];
  const float* Wq    = (const float*)d_in[3];
  const float* Wk    = (const float*)d_in[4];
  const float* Wv    = (const float*)d_in[5];

  float* out_ctx  = (float*)d_out;
  float* out_attn = (float*)d_out + 16777216;

  unsigned short* X   = (unsigned short*)d_ws;
  unsigned short* q_s = X + 16777216;
  unsigned short* k_s = q_s + 16777216;
  unsigned short* v_s = k_s + 16777216;
  unsigned short* Wbf = v_s + 16777216;
  unsigned short* v_t = X;  // alias (X dead after proj v)

  prep_w_kernel<<<768, 256, 0, stream>>>(Wq, Wk, Wv, Wbf);

  prep_x_kernel<<<4096, 256, 0, stream>>>(query, X);
  gemm_proj_kernel<<<dim3(512, 2), 256, 0, stream>>>(X, Wbf, q_s);

  prep_x_kernel<<<4096, 256, 0, stream>>>(key, X);
  gemm_proj_kernel<<<dim3(512, 2), 256, 0, stream>>>(X, Wbf + 65536, k_s);

  prep_x_kernel<<<4096, 256, 0, stream>>>(value, X);
  gemm_proj_kernel<<<dim3(512, 2), 256, 0, stream>>>(X, Wbf + 131072, v_s);

  gemm_score_kernel<<<dim3(16, 16, 16), 256, 0, stream>>>(q_s, k_s, out_attn);
  softmax_kernel<<<32768, 256, 0, stream>>>(out_attn);
  transpose_v_kernel<<<dim3(32, 8, 16), 256, 0, stream>>>(v_s, v_t);
  gemm_ctx_kernel<<<dim3(16, 4, 16), 256, 0, stream>>>(out_attn, v_t, out_ctx);
}

// Round 3
// 556.518 us; speedup vs baseline: 1.0364x; 1.0364x over previous
//
#include <hip/hip_runtime.h>

// MultiHeadAttention (B=2, L=2048, C=256, H=W=4, NH=8, DH=32)
// R3: softmax emits bf16 P; context GEMM is pure bf16 async (global_load_lds both
//     operands). Falls back to fp32-A ctx (scalar cast) if ws_size too small.
//
// Workspace (shorts):
//   X    @ 0           : 16,777,216   (reused; later v_t)
//   q_s  @ 16,777,216  : 16,777,216   [bh][l][512]
//   k_s  @ 33,554,432  : 16,777,216
//   v_s  @ 50,331,648  : 16,777,216
//   Wbf  @ 67,108,864  : 196,608
//   P_bf @ 67,305,472  : 67,108,864   (only if ws_size >= 268,828,672 B)

typedef short s16x8 __attribute__((ext_vector_type(8)));
typedef float f32x4 __attribute__((ext_vector_type(4)));

__device__ __forceinline__ unsigned short f2bf(float f) {
  union { float f; unsigned int u; } v; v.f = f;
  return (unsigned short)((v.u + 0x7FFFu + ((v.u >> 16) & 1u)) >> 16);  // RNE
}

// async global->LDS, 16B per lane; lds base wave-uniform (HW adds lane*16)
__device__ __forceinline__ void async_copy16(const unsigned short* g, unsigned short* l) {
  __builtin_amdgcn_global_load_lds((const __attribute__((address_space(1))) void*)g,
                                   (__attribute__((address_space(3))) void*)l, 16, 0, 0);
}

// ---------------- prep: (B,L,C,H,W) fp32 -> X[(b,l,hw)][c] bf16 ----------------
__global__ void __launch_bounds__(256) prep_x_kernel(const float* __restrict__ src,
                                                     unsigned short* __restrict__ dst) {
  __shared__ float ld[256 * 17];
  const int bl = blockIdx.x;
  const int t = threadIdx.x;
  const float* s = src + (size_t)bl * 4096;
#pragma unroll
  for (int i = 0; i < 4; ++i) {
    int flat = i * 1024 + t * 4;
    float4 v = *(const float4*)(s + flat);
    int c = flat >> 4, hw = flat & 15;
    float* p = &ld[c * 17 + hw];
    p[0] = v.x; p[1] = v.y; p[2] = v.z; p[3] = v.w;
  }
  __syncthreads();
  unsigned short* d = dst + (size_t)bl * 4096;
#pragma unroll
  for (int hw = 0; hw < 16; ++hw)
    d[hw * 256 + t] = f2bf(ld[t * 17 + hw]);
}

__global__ void __launch_bounds__(256) prep_w_kernel(const float* __restrict__ a,
                                                     const float* __restrict__ b,
                                                     const float* __restrict__ c,
                                                     unsigned short* __restrict__ dst) {
  int i = blockIdx.x * 256 + threadIdx.x;
  const float* s = (i < 65536) ? a : ((i < 131072) ? b : c);
  dst[i] = f2bf(s[i & 65535]);
}

// ---------------- shared async GEMM core: C(128x128) += A(128xK) * Bt(128xK)^T ----------------
__device__ __forceinline__ void gemm_core_async(const unsigned short* __restrict__ Ag, int ldA,
                                                const unsigned short* __restrict__ Bg, int ldB,
                                                int K, unsigned short* As, unsigned short* Bs,
                                                f32x4 acc[4][4]) {
  const int tid = threadIdx.x;
  const int lane = tid & 63;
  const int w = tid >> 6;
  const int wr = (w >> 1) * 64, wc = (w & 1) * 64;
  const int r = lane >> 2, kk = (lane & 3) * 8;
  for (int k0 = 0; k0 < K; k0 += 32) {
#pragma unroll
    for (int i = 0; i < 2; ++i) {
      const int row0 = w * 32 + i * 16;
      async_copy16(Ag + (size_t)(row0 + r) * ldA + k0 + kk, As + row0 * 32);
      async_copy16(Bg + (size_t)(row0 + r) * ldB + k0 + kk, Bs + row0 * 32);
    }
    __syncthreads();
    s16x8 af[4], bfv[4];
#pragma unroll
    for (int m = 0; m < 4; ++m)
      af[m] = *(const s16x8*)(As + (wr + m * 16 + (lane & 15)) * 32 + (lane >> 4) * 8);
#pragma unroll
    for (int n = 0; n < 4; ++n)
      bfv[n] = *(const s16x8*)(Bs + (wc + n * 16 + (lane & 15)) * 32 + (lane >> 4) * 8);
#pragma unroll
    for (int m = 0; m < 4; ++m)
#pragma unroll
      for (int n = 0; n < 4; ++n)
        acc[m][n] = __builtin_amdgcn_mfma_f32_16x16x32_bf16(af[m], bfv[n], acc[m][n], 0, 0, 0);
    __syncthreads();
  }
}

#define ACC_INIT(acc)                         \
  {                                           \
    const f32x4 z_ = {0.f, 0.f, 0.f, 0.f};    \
    _Pragma("unroll")                         \
    for (int m_ = 0; m_ < 4; ++m_)            \
      _Pragma("unroll")                       \
      for (int n_ = 0; n_ < 4; ++n_) acc[m_][n_] = z_; \
  }

// ---------------- projection: X(65536x256) * W(256x256)^T -> q_s[bh][l][512] bf16 ----------------
__global__ void __launch_bounds__(256) gemm_proj_kernel(const unsigned short* __restrict__ X,
                                                        const unsigned short* __restrict__ W,
                                                        unsigned short* __restrict__ out) {
  __shared__ unsigned short As[4096], Bs[4096];
  f32x4 acc[4][4];
  ACC_INIT(acc);
  gemm_core_async(X + (size_t)blockIdx.x * 128 * 256, 256,
                  W + (size_t)blockIdx.y * 128 * 256, 256, 256, As, Bs, acc);
  const int tid = threadIdx.x, lane = tid & 63, w = tid >> 6;
  const int wr = (w >> 1) * 64, wc = (w & 1) * 64;
  const int R0 = blockIdx.x * 128 + wr + ((lane >> 4) << 2);
  const int C0 = blockIdx.y * 128 + wc + (lane & 15);
#pragma unroll
  for (int m = 0; m < 4; ++m)
#pragma unroll
    for (int n = 0; n < 4; ++n)
#pragma unroll
      for (int r = 0; r < 4; ++r) {
        int R = R0 + m * 16 + r;
        int o = C0 + n * 16;
        int bl = R >> 4, hw = R & 15;
        int b = bl >> 11, l = bl & 2047;
        int head = o >> 5, d = o & 31;
        out[((size_t)(head * 2 + b) * 2048 + l) * 512 + d * 16 + hw] = f2bf(acc[m][n][r]);
      }
}

// ---------------- score: q_s[bh] (2048x512) * k_s[bh]^T -> attn (raw, scaled) fp32 ----------------
__global__ void __launch_bounds__(256) gemm_score_kernel(const unsigned short* __restrict__ q,
                                                         const unsigned short* __restrict__ k,
                                                         float* __restrict__ attn) {
  __shared__ unsigned short As[4096], Bs[4096];
  f32x4 acc[4][4];
  ACC_INIT(acc);
  const int bh = blockIdx.z;
  gemm_core_async(q + ((size_t)bh * 2048 + blockIdx.x * 128) * 512, 512,
                  k + ((size_t)bh * 2048 + blockIdx.y * 128) * 512, 512, 512, As, Bs, acc);
  const int tid = threadIdx.x, lane = tid & 63, w = tid >> 6;
  const int wr = (w >> 1) * 64, wc = (w & 1) * 64;
  float* O = attn + (size_t)bh * 2048 * 2048;
  const float scale = 0.17677669529663687f;  // 1/sqrt(32)
  const int R0 = blockIdx.x * 128 + wr + ((lane >> 4) << 2);
  const int C0 = blockIdx.y * 128 + wc + (lane & 15);
#pragma unroll
  for (int m = 0; m < 4; ++m)
#pragma unroll
    for (int n = 0; n < 4; ++n)
#pragma unroll
      for (int r = 0; r < 4; ++r)
        O[(size_t)(R0 + m * 16 + r) * 2048 + (C0 + n * 16)] = acc[m][n][r] * scale;
}

// ---------------- softmax over rows of attn (in place), optional bf16 P output ----------------
template <int WRITE_P>
__global__ void __launch_bounds__(256) softmax_kernel(float* __restrict__ attn,
                                                      unsigned short* __restrict__ pbf) {
  __shared__ float red[4];
  float* p = attn + (size_t)blockIdx.x * 2048;
  const int t = threadIdx.x;
  float4 v0 = *(const float4*)(p + t * 8);
  float4 v1 = *(const float4*)(p + t * 8 + 4);
  float mx = fmaxf(fmaxf(fmaxf(v0.x, v0.y), fmaxf(v0.z, v0.w)),
                   fmaxf(fmaxf(v1.x, v1.y), fmaxf(v1.z, v1.w)));
#pragma unroll
  for (int off = 32; off; off >>= 1) mx = fmaxf(mx, __shfl_xor(mx, off));
  if ((t & 63) == 0) red[t >> 6] = mx;
  __syncthreads();
  mx = fmaxf(fmaxf(red[0], red[1]), fmaxf(red[2], red[3]));
  __syncthreads();
  float e[8];
  e[0] = __expf(v0.x - mx); e[1] = __expf(v0.y - mx);
  e[2] = __expf(v0.z - mx); e[3] = __expf(v0.w - mx);
  e[4] = __expf(v1.x - mx); e[5] = __expf(v1.y - mx);
  e[6] = __expf(v1.z - mx); e[7] = __expf(v1.w - mx);
  float s = ((e[0] + e[1]) + (e[2] + e[3])) + ((e[4] + e[5]) + (e[6] + e[7]));
#pragma unroll
  for (int off = 32; off; off >>= 1) s += __shfl_xor(s, off);
  if ((t & 63) == 0) red[t >> 6] = s;
  __syncthreads();
  s = red[0] + red[1] + red[2] + red[3];
  const float inv = 1.0f / s;
  float o[8] = {e[0] * inv, e[1] * inv, e[2] * inv, e[3] * inv,
                e[4] * inv, e[5] * inv, e[6] * inv, e[7] * inv};
  *(float4*)(p + t * 8)     = *(float4*)&o[0];
  *(float4*)(p + t * 8 + 4) = *(float4*)&o[4];
  if (WRITE_P) {
    s16x8 h;
#pragma unroll
    for (int i = 0; i < 8; ++i) h[i] = (short)f2bf(o[i]);
    *(s16x8*)(pbf + (size_t)blockIdx.x * 2048 + t * 8) = h;
  }
}

// ---------------- v_s[bh][j][dd] -> v_t[bh][dd][j] (bf16 transpose) ----------------
__global__ void __launch_bounds__(256) transpose_v_kernel(const unsigned short* __restrict__ vs,
                                                          unsigned short* __restrict__ vt) {
  __shared__ unsigned short tile[64][65];
  const int bh = blockIdx.z;
  const int j0 = blockIdx.x * 64, d0 = blockIdx.y * 64;
  const unsigned short* src = vs + (size_t)bh * 2048 * 512;
  unsigned short* dst = vt + (size_t)bh * 512 * 2048;
  const int t = threadIdx.x;
#pragma unroll
  for (int i = 0; i < 16; ++i) {
    int e = t * 16 + i;
    int r = e >> 6, c = e & 63;
    tile[r][c] = src[(size_t)(j0 + r) * 512 + d0 + c];
  }
  __syncthreads();
#pragma unroll
  for (int i = 0; i < 16; ++i) {
    int e = t * 16 + i;
    int r = e >> 6, c = e & 63;
    dst[(size_t)(d0 + r) * 2048 + j0 + c] = tile[c][r];
  }
}

// ---------------- ctx epilogue (shared) ----------------
__device__ __forceinline__ void ctx_epilogue(f32x4 acc[4][4], float* __restrict__ outc,
                                             int bh, int bx, int by) {
  const int tid = threadIdx.x, lane = tid & 63, w = tid >> 6;
  const int wr = (w >> 1) * 64, wc = (w & 1) * 64;
  const int b = bh & 1, head = bh >> 1;
  const int R0 = bx * 128 + wr + ((lane >> 4) << 2);
  const int C0 = by * 128 + wc + (lane & 15);
#pragma unroll
  for (int m = 0; m < 4; ++m)
#pragma unroll
    for (int n = 0; n < 4; ++n)
#pragma unroll
      for (int r2 = 0; r2 < 4; ++r2) {
        int R = R0 + m * 16 + r2;
        int dd = C0 + n * 16;
        int d = dd >> 4, hw = dd & 15;
        outc[((size_t)(b * 2048 + R) * 256 + head * 32 + d) * 16 + hw] = acc[m][n][r2];
      }
}

// ---------------- context (bf16 P path): P_bf(2048x2048) * v_t^T -> out ----------------
__global__ void __launch_bounds__(256) gemm_ctx_bf16_kernel(const unsigned short* __restrict__ pbf,
                                                            const unsigned short* __restrict__ vt,
                                                            float* __restrict__ outc) {
  __shared__ unsigned short As[4096], Bs[4096];
  f32x4 acc[4][4];
  ACC_INIT(acc);
  const int bh = blockIdx.z;
  gemm_core_async(pbf + (size_t)bh * 4194304 + (size_t)blockIdx.x * 128 * 2048, 2048,
                  vt + (size_t)bh * 1048576 + (size_t)blockIdx.y * 128 * 2048, 2048,
                  2048, As, Bs, acc);
  ctx_epilogue(acc, outc, bh, blockIdx.x, blockIdx.y);
}

// ---------------- context (fallback): attn fp32 * v_t^T -> out ----------------
__global__ void __launch_bounds__(256) gemm_ctx_f32_kernel(const float* __restrict__ attn,
                                                           const unsigned short* __restrict__ vt,
                                                           float* __restrict__ outc) {
  __shared__ unsigned short As[4096], Bs[4096];
  f32x4 acc[4][4];
  ACC_INIT(acc);
  const int tid = threadIdx.x, lane = tid & 63, w = tid >> 6;
  const int wr = (w >> 1) * 64, wc = (w & 1) * 64;
  const int bh = blockIdx.z;
  const float* Ag = attn + (size_t)bh * 4194304 + (size_t)blockIdx.x * 128 * 2048;
  const unsigned short* Bg = vt + (size_t)bh * 1048576 + (size_t)blockIdx.y * 128 * 2048;
  const int r = lane >> 2, kk = (lane & 3) * 8;
  const int arow = tid >> 1, acol = (tid & 1) * 16;
  for (int k0 = 0; k0 < 2048; k0 += 32) {
#pragma unroll
    for (int i = 0; i < 2; ++i) {
      const int row0 = w * 32 + i * 16;
      async_copy16(Bg + (size_t)(row0 + r) * 2048 + k0 + kk, Bs + row0 * 32);
    }
    {
      const float* sp = Ag + (size_t)arow * 2048 + k0 + acol;
      float4 f0 = *(const float4*)(sp);
      float4 f1 = *(const float4*)(sp + 4);
      float4 f2 = *(const float4*)(sp + 8);
      float4 f3 = *(const float4*)(sp + 12);
      s16x8 h0, h1;
      h0[0] = (short)f2bf(f0.x); h0[1] = (short)f2bf(f0.y);
      h0[2] = (short)f2bf(f0.z); h0[3] = (short)f2bf(f0.w);
      h0[4] = (short)f2bf(f1.x); h0[5] = (short)f2bf(f1.y);
      h0[6] = (short)f2bf(f1.z); h0[7] = (short)f2bf(f1.w);
      h1[0] = (short)f2bf(f2.x); h1[1] = (short)f2bf(f2.y);
      h1[2] = (short)f2bf(f2.z); h1[3] = (short)f2bf(f2.w);
      h1[4] = (short)f2bf(f3.x); h1[5] = (short)f2bf(f3.y);
      h1[6] = (short)f2bf(f3.z); h1[7] = (short)f2bf(f3.w);
      *(s16x8*)(As + arow * 32 + acol) = h0;
      *(s16x8*)(As + arow * 32 + acol + 8) = h1;
    }
    __syncthreads();
    s16x8 af[4], bfv[4];
#pragma unroll
    for (int m = 0; m < 4; ++m)
      af[m] = *(const s16x8*)(As + (wr + m * 16 + (lane & 15)) * 32 + (lane >> 4) * 8);
#pragma unroll
    for (int n = 0; n < 4; ++n)
      bfv[n] = *(const s16x8*)(Bs + (wc + n * 16 + (lane & 15)) * 32 + (lane >> 4) * 8);
#pragma unroll
    for (int m = 0; m < 4; ++m)
#pragma unroll
      for (int n = 0; n < 4; ++n)
        acc[m][n] = __builtin_amdgcn_mfma_f32_16x16x32_bf16(af[m], bfv[n], acc[m][n], 0, 0, 0);
    __syncthreads();
  }
  ctx_epilogue(acc, outc, bh, blockIdx.x, blockIdx.y);
}

extern "C" void kernel_launch(void* const* d_in, const int* in_sizes, int n_in,
                              void* d_out, int out_size, void* d_ws, size_t ws_size,
                              hipStream_t stream) {
  const float* query = (const float*)d_in[0];
  const float* key   = (const float*)d_in[1];
  const float* value = (const float*)d_in[2];
  const float* Wq    = (const float*)d_in[3];
  const float* Wk    = (const float*)d_in[4];
  const float* Wv    = (const float*)d_in[5];

  float* out_ctx  = (float*)d_out;
  float* out_attn = (float*)d_out + 16777216;

  unsigned short* X   = (unsigned short*)d_ws;
  unsigned short* q_s = X + 16777216;
  unsigned short* k_s = q_s + 16777216;
  unsigned short* v_s = k_s + 16777216;
  unsigned short* Wbf = v_s + 16777216;               // 196,608 shorts
  unsigned short* P_bf = Wbf + 196608;                // 67,108,864 shorts
  unsigned short* v_t = X;                            // alias (X dead after proj v)

  const bool use_p = ws_size >= (size_t)(134414336) * 2;  // 268,828,672 B

  prep_w_kernel<<<768, 256, 0, stream>>>(Wq, Wk, Wv, Wbf);

  prep_x_kernel<<<4096, 256, 0, stream>>>(query, X);
  gemm_proj_kernel<<<dim3(512, 2), 256, 0, stream>>>(X, Wbf, q_s);

  prep_x_kernel<<<4096, 256, 0, stream>>>(key, X);
  gemm_proj_kernel<<<dim3(512, 2), 256, 0, stream>>>(X, Wbf + 65536, k_s);

  prep_x_kernel<<<4096, 256, 0, stream>>>(value, X);
  gemm_proj_kernel<<<dim3(512, 2), 256, 0, stream>>>(X, Wbf + 131072, v_s);

  gemm_score_kernel<<<dim3(16, 16, 16), 256, 0, stream>>>(q_s, k_s, out_attn);
  if (use_p)
    softmax_kernel<1><<<32768, 256, 0, stream>>>(out_attn, P_bf);
  else
    softmax_kernel<0><<<32768, 256, 0, stream>>>(out_attn, nullptr);
  transpose_v_kernel<<<dim3(32, 8, 16), 256, 0, stream>>>(v_s, v_t);
  if (use_p)
    gemm_ctx_bf16_kernel<<<dim3(16, 4, 16), 256, 0, stream>>>(P_bf, v_t, out_ctx);
  else
    gemm_ctx_f32_kernel<<<dim3(16, 4, 16), 256, 0, stream>>>(out_attn, v_t, out_ctx);
}

// Round 4
// 478.540 us; speedup vs baseline: 1.2053x; 1.1630x over previous
//
#include <hip/hip_runtime.h>

// MultiHeadAttention (B=2, L=2048, C=256, H=W=4, NH=8, DH=32)
// R4: no-max softmax fused into score epilogue (P_bf + partial row sums),
//     normalize kernel produces attn fp32 + inv[]; ctx scales by inv in epilogue;
//     V projection writes v_t directly (transposed GEMM), transpose_v removed.
//
// Workspace (shorts):
//   X     @ 0           : 16,777,216   (Q/K prep; X2 for V; fallback v_t alias)
//   q_s   @ 16,777,216  : 16,777,216   [bh][l][512]
//   k_s   @ 33,554,432  : 16,777,216
//   v_t   @ 50,331,648  : 16,777,216   [bh][dd][l]  (fallback: v_s [bh][l][dd])
//   Wbf   @ 67,108,864  : 196,608
//   P_bf  @ 67,305,472  : 67,108,864   bf16 exp(scores)
//   part  @ 134,414,336 : 2,097,152    (1,048,576 fp32: [row32768][32])
//   inv   @ 136,511,488 : 65,536       (32,768 fp32)
// Main path needs ws_size >= 273,154,048 B (falls back to R3 otherwise).

typedef short s16x8 __attribute__((ext_vector_type(8)));
typedef float f32x4 __attribute__((ext_vector_type(4)));

__device__ __forceinline__ unsigned short f2bf(float f) {
  union { float f; unsigned int u; } v; v.f = f;
  return (unsigned short)((v.u + 0x7FFFu + ((v.u >> 16) & 1u)) >> 16);  // RNE
}
__device__ __forceinline__ float bf2f(unsigned short h) {
  union { unsigned int u; float f; } v; v.u = ((unsigned int)h) << 16;
  return v.f;
}

// async global->LDS, 16B per lane; lds base wave-uniform (HW adds lane*16)
__device__ __forceinline__ void async_copy16(const unsigned short* g, unsigned short* l) {
  __builtin_amdgcn_global_load_lds((const __attribute__((address_space(1))) void*)g,
                                   (__attribute__((address_space(3))) void*)l, 16, 0, 0);
}

// ---------------- prep: (B,L,C,H,W) fp32 -> X[(b,l,hw)][c] bf16 ----------------
__global__ void __launch_bounds__(256) prep_x_kernel(const float* __restrict__ src,
                                                     unsigned short* __restrict__ dst) {
  __shared__ float ld[256 * 17];
  const int bl = blockIdx.x;
  const int t = threadIdx.x;
  const float* s = src + (size_t)bl * 4096;
#pragma unroll
  for (int i = 0; i < 4; ++i) {
    int flat = i * 1024 + t * 4;
    float4 v = *(const float4*)(s + flat);
    int c = flat >> 4, hw = flat & 15;
    float* p = &ld[c * 17 + hw];
    p[0] = v.x; p[1] = v.y; p[2] = v.z; p[3] = v.w;
  }
  __syncthreads();
  unsigned short* d = dst + (size_t)bl * 4096;
#pragma unroll
  for (int hw = 0; hw < 16; ++hw)
    d[hw * 256 + t] = f2bf(ld[t * 17 + hw]);
}

// ---------------- prep V: (B,L,C,H,W) fp32 -> X2[(b,hw,l)][c] bf16 ----------------
__global__ void __launch_bounds__(256) prep_xv_kernel(const float* __restrict__ src,
                                                      unsigned short* __restrict__ dst) {
  __shared__ float ld[256 * 17];
  const int bl = blockIdx.x;
  const int b = bl >> 11, l = bl & 2047;
  const int t = threadIdx.x;
  const float* s = src + (size_t)bl * 4096;
#pragma unroll
  for (int i = 0; i < 4; ++i) {
    int flat = i * 1024 + t * 4;
    float4 v = *(const float4*)(s + flat);
    int c = flat >> 4, hw = flat & 15;
    float* p = &ld[c * 17 + hw];
    p[0] = v.x; p[1] = v.y; p[2] = v.z; p[3] = v.w;
  }
  __syncthreads();
#pragma unroll
  for (int hw = 0; hw < 16; ++hw)
    dst[((size_t)(b * 16 + hw) * 2048 + l) * 256 + t] = f2bf(ld[t * 17 + hw]);
}

__global__ void __launch_bounds__(256) prep_w_kernel(const float* __restrict__ a,
                                                     const float* __restrict__ b,
                                                     const float* __restrict__ c,
                                                     unsigned short* __restrict__ dst) {
  int i = blockIdx.x * 256 + threadIdx.x;
  const float* s = (i < 65536) ? a : ((i < 131072) ? b : c);
  dst[i] = f2bf(s[i & 65535]);
}

// ---------------- shared async GEMM core: C(128x128) += A(128xK) * Bt(128xK)^T ----------------
__device__ __forceinline__ void gemm_core_async(const unsigned short* __restrict__ Ag, int ldA,
                                                const unsigned short* __restrict__ Bg, int ldB,
                                                int K, unsigned short* As, unsigned short* Bs,
                                                f32x4 acc[4][4]) {
  const int tid = threadIdx.x;
  const int lane = tid & 63;
  const int w = tid >> 6;
  const int wr = (w >> 1) * 64, wc = (w & 1) * 64;
  const int r = lane >> 2, kk = (lane & 3) * 8;
  for (int k0 = 0; k0 < K; k0 += 32) {
#pragma unroll
    for (int i = 0; i < 2; ++i) {
      const int row0 = w * 32 + i * 16;
      async_copy16(Ag + (size_t)(row0 + r) * ldA + k0 + kk, As + row0 * 32);
      async_copy16(Bg + (size_t)(row0 + r) * ldB + k0 + kk, Bs + row0 * 32);
    }
    __syncthreads();
    s16x8 af[4], bfv[4];
#pragma unroll
    for (int m = 0; m < 4; ++m)
      af[m] = *(const s16x8*)(As + (wr + m * 16 + (lane & 15)) * 32 + (lane >> 4) * 8);
#pragma unroll
    for (int n = 0; n < 4; ++n)
      bfv[n] = *(const s16x8*)(Bs + (wc + n * 16 + (lane & 15)) * 32 + (lane >> 4) * 8);
#pragma unroll
    for (int m = 0; m < 4; ++m)
#pragma unroll
      for (int n = 0; n < 4; ++n)
        acc[m][n] = __builtin_amdgcn_mfma_f32_16x16x32_bf16(af[m], bfv[n], acc[m][n], 0, 0, 0);
    __syncthreads();
  }
}

#define ACC_INIT(acc)                         \
  {                                           \
    const f32x4 z_ = {0.f, 0.f, 0.f, 0.f};    \
    _Pragma("unroll")                         \
    for (int m_ = 0; m_ < 4; ++m_)            \
      _Pragma("unroll")                       \
      for (int n_ = 0; n_ < 4; ++n_) acc[m_][n_] = z_; \
  }

// ---------------- projection: X(65536x256) * W(256x256)^T -> q_s[bh][l][512] bf16 ----------------
__global__ void __launch_bounds__(256) gemm_proj_kernel(const unsigned short* __restrict__ X,
                                                        const unsigned short* __restrict__ W,
                                                        unsigned short* __restrict__ out) {
  __shared__ unsigned short As[4096], Bs[4096];
  f32x4 acc[4][4];
  ACC_INIT(acc);
  gemm_core_async(X + (size_t)blockIdx.x * 128 * 256, 256,
                  W + (size_t)blockIdx.y * 128 * 256, 256, 256, As, Bs, acc);
  const int tid = threadIdx.x, lane = tid & 63, w = tid >> 6;
  const int wr = (w >> 1) * 64, wc = (w & 1) * 64;
  const int R0 = blockIdx.x * 128 + wr + ((lane >> 4) << 2);
  const int C0 = blockIdx.y * 128 + wc + (lane & 15);
#pragma unroll
  for (int m = 0; m < 4; ++m)
#pragma unroll
    for (int n = 0; n < 4; ++n)
#pragma unroll
      for (int r = 0; r < 4; ++r) {
        int R = R0 + m * 16 + r;          // p = (b*L+l)*16 + hw
        int o = C0 + n * 16;
        int bl = R >> 4, hw = R & 15;
        int b = bl >> 11, l = bl & 2047;
        int head = o >> 5, d = o & 31;
        out[((size_t)(head * 2 + b) * 2048 + l) * 512 + d * 16 + hw] = f2bf(acc[m][n][r]);
      }
}

// ---------------- V projection (transposed): W(256x256) x X2(65536x256)^T -> v_t[bh][dd][l] ----------------
__global__ void __launch_bounds__(256) gemm_proj_vt_kernel(const unsigned short* __restrict__ W,
                                                           const unsigned short* __restrict__ X2,
                                                           unsigned short* __restrict__ vt) {
  __shared__ unsigned short As[4096], Bs[4096];
  f32x4 acc[4][4];
  ACC_INIT(acc);
  gemm_core_async(W + (size_t)blockIdx.x * 128 * 256, 256,
                  X2 + (size_t)blockIdx.y * 128 * 256, 256, 256, As, Bs, acc);
  const int tid = threadIdx.x, lane = tid & 63, w = tid >> 6;
  const int wr = (w >> 1) * 64, wc = (w & 1) * 64;
  const int R0 = blockIdx.x * 128 + wr + ((lane >> 4) << 2);   // o rows
  const int C0 = blockIdx.y * 128 + wc + (lane & 15);          // p' cols
#pragma unroll
  for (int m = 0; m < 4; ++m)
#pragma unroll
    for (int n = 0; n < 4; ++n)
#pragma unroll
      for (int r = 0; r < 4; ++r) {
        int o = R0 + m * 16 + r;          // channel: head*32 + d
        int p = C0 + n * 16;              // (b*16+hw)*2048 + l
        int head = o >> 5, d = o & 31;
        int b = p >> 15, hw = (p >> 11) & 15, l = p & 2047;
        vt[((size_t)((head * 2 + b) * 512) + d * 16 + hw) * 2048 + l] = f2bf(acc[m][n][r]);
      }
}

// ---------------- score: q*k^T; FUSED: P_bf=bf16(exp(s)) + partial row sums ----------------
template <int FUSED>
__global__ void __launch_bounds__(256) gemm_score_kernel(const unsigned short* __restrict__ q,
                                                         const unsigned short* __restrict__ k,
                                                         float* __restrict__ attn,
                                                         unsigned short* __restrict__ pbf,
                                                         float* __restrict__ partial) {
  __shared__ unsigned short As[4096], Bs[4096];
  f32x4 acc[4][4];
  ACC_INIT(acc);
  const int bh = blockIdx.z;
  gemm_core_async(q + ((size_t)bh * 2048 + blockIdx.x * 128) * 512, 512,
                  k + ((size_t)bh * 2048 + blockIdx.y * 128) * 512, 512, 512, As, Bs, acc);
  const int tid = threadIdx.x, lane = tid & 63, w = tid >> 6;
  const int wr = (w >> 1) * 64, wc = (w & 1) * 64;
  const float scale = 0.17677669529663687f;  // 1/sqrt(32)
  const int R0 = blockIdx.x * 128 + wr + ((lane >> 4) << 2);
  const int C0 = blockIdx.y * 128 + wc + (lane & 15);
  if (!FUSED) {
    float* O = attn + (size_t)bh * 4194304;
#pragma unroll
    for (int m = 0; m < 4; ++m)
#pragma unroll
      for (int n = 0; n < 4; ++n)
#pragma unroll
        for (int r = 0; r < 4; ++r)
          O[(size_t)(R0 + m * 16 + r) * 2048 + (C0 + n * 16)] = acc[m][n][r] * scale;
  } else {
    // e = exp(s*scale), no max subtraction (|s*scale| <~ 8, overflow-safe)
#pragma unroll
    for (int m = 0; m < 4; ++m)
#pragma unroll
      for (int n = 0; n < 4; ++n)
#pragma unroll
        for (int r = 0; r < 4; ++r)
          acc[m][n][r] = __expf(acc[m][n][r] * scale);
    unsigned short* P = pbf + (size_t)bh * 4194304;
#pragma unroll
    for (int m = 0; m < 4; ++m)
#pragma unroll
      for (int n = 0; n < 4; ++n)
#pragma unroll
        for (int r = 0; r < 4; ++r)
          P[(size_t)(R0 + m * 16 + r) * 2048 + (C0 + n * 16)] = f2bf(acc[m][n][r]);
    const int chunk = blockIdx.y * 2 + (w & 1);
#pragma unroll
    for (int m = 0; m < 4; ++m)
#pragma unroll
      for (int r = 0; r < 4; ++r) {
        float s = (acc[m][0][r] + acc[m][1][r]) + (acc[m][2][r] + acc[m][3][r]);
        s += __shfl_xor(s, 1); s += __shfl_xor(s, 2);
        s += __shfl_xor(s, 4); s += __shfl_xor(s, 8);
        if ((lane & 15) == 0) {
          int rloc = wr + ((lane >> 4) << 2) + m * 16 + r;
          partial[((size_t)bh * 2048 + blockIdx.x * 128 + rloc) * 32 + chunk] = s;
        }
      }
  }
}

// ---------------- normalize: attn = P_bf * inv(rowsum); writes inv[] ----------------
__global__ void __launch_bounds__(256) norm_kernel(const unsigned short* __restrict__ pbf,
                                                   const float* __restrict__ partial,
                                                   float* __restrict__ attn,
                                                   float* __restrict__ inv_buf) {
  __shared__ float sh;
  const int row = blockIdx.x;          // bh*2048 + i
  const int t = threadIdx.x;
  if (t < 32) {
    float v = partial[(size_t)row * 32 + t];
    v += __shfl_xor(v, 1); v += __shfl_xor(v, 2);
    v += __shfl_xor(v, 4); v += __shfl_xor(v, 8); v += __shfl_xor(v, 16);
    if (t == 0) sh = v;
  }
  __syncthreads();
  const float inv = 1.0f / sh;
  if (t == 0) inv_buf[row] = inv;
  s16x8 h = *(const s16x8*)(pbf + (size_t)row * 2048 + t * 8);
  float o[8];
#pragma unroll
  for (int i = 0; i < 8; ++i) o[i] = bf2f((unsigned short)h[i]) * inv;
  float* p = attn + (size_t)row * 2048 + t * 8;
  *(float4*)(p)     = *(float4*)&o[0];
  *(float4*)(p + 4) = *(float4*)&o[4];
}

// ---------------- fallback softmax (R3) ----------------
__global__ void __launch_bounds__(256) softmax_kernel(float* __restrict__ attn) {
  __shared__ float red[4];
  float* p = attn + (size_t)blockIdx.x * 2048;
  const int t = threadIdx.x;
  float4 v0 = *(const float4*)(p + t * 8);
  float4 v1 = *(const float4*)(p + t * 8 + 4);
  float mx = fmaxf(fmaxf(fmaxf(v0.x, v0.y), fmaxf(v0.z, v0.w)),
                   fmaxf(fmaxf(v1.x, v1.y), fmaxf(v1.z, v1.w)));
#pragma unroll
  for (int off = 32; off; off >>= 1) mx = fmaxf(mx, __shfl_xor(mx, off));
  if ((t & 63) == 0) red[t >> 6] = mx;
  __syncthreads();
  mx = fmaxf(fmaxf(red[0], red[1]), fmaxf(red[2], red[3]));
  __syncthreads();
  float e[8];
  e[0] = __expf(v0.x - mx); e[1] = __expf(v0.y - mx);
  e[2] = __expf(v0.z - mx); e[3] = __expf(v0.w - mx);
  e[4] = __expf(v1.x - mx); e[5] = __expf(v1.y - mx);
  e[6] = __expf(v1.z - mx); e[7] = __expf(v1.w - mx);
  float s = ((e[0] + e[1]) + (e[2] + e[3])) + ((e[4] + e[5]) + (e[6] + e[7]));
#pragma unroll
  for (int off = 32; off; off >>= 1) s += __shfl_xor(s, off);
  if ((t & 63) == 0) red[t >> 6] = s;
  __syncthreads();
  s = red[0] + red[1] + red[2] + red[3];
  const float inv = 1.0f / s;
  float4 o0 = {e[0] * inv, e[1] * inv, e[2] * inv, e[3] * inv};
  float4 o1 = {e[4] * inv, e[5] * inv, e[6] * inv, e[7] * inv};
  *(float4*)(p + t * 8) = o0;
  *(float4*)(p + t * 8 + 4) = o1;
}

// ---------------- fallback v_s -> v_t transpose ----------------
__global__ void __launch_bounds__(256) transpose_v_kernel(const unsigned short* __restrict__ vs,
                                                          unsigned short* __restrict__ vt) {
  __shared__ unsigned short tile[64][65];
  const int bh = blockIdx.z;
  const int j0 = blockIdx.x * 64, d0 = blockIdx.y * 64;
  const unsigned short* src = vs + (size_t)bh * 2048 * 512;
  unsigned short* dst = vt + (size_t)bh * 512 * 2048;
  const int t = threadIdx.x;
#pragma unroll
  for (int i = 0; i < 16; ++i) {
    int e = t * 16 + i;
    int r = e >> 6, c = e & 63;
    tile[r][c] = src[(size_t)(j0 + r) * 512 + d0 + c];
  }
  __syncthreads();
#pragma unroll
  for (int i = 0; i < 16; ++i) {
    int e = t * 16 + i;
    int r = e >> 6, c = e & 63;
    dst[(size_t)(d0 + r) * 2048 + j0 + c] = tile[c][r];
  }
}

// ---------------- ctx epilogue (shared; optional inv scaling) ----------------
__device__ __forceinline__ void ctx_epilogue(f32x4 acc[4][4], float* __restrict__ outc,
                                             const float* __restrict__ inv_buf,
                                             int bh, int bx, int by) {
  const int tid = threadIdx.x, lane = tid & 63, w = tid >> 6;
  const int wr = (w >> 1) * 64, wc = (w & 1) * 64;
  const int b = bh & 1, head = bh >> 1;
  const int R0 = bx * 128 + wr + ((lane >> 4) << 2);
  const int C0 = by * 128 + wc + (lane & 15);
#pragma unroll
  for (int m = 0; m < 4; ++m)
#pragma unroll
    for (int r2 = 0; r2 < 4; ++r2) {
      int R = R0 + m * 16 + r2;
      float sc = inv_buf ? inv_buf[(size_t)bh * 2048 + R] : 1.0f;
#pragma unroll
      for (int n = 0; n < 4; ++n) {
        int dd = C0 + n * 16;
        int d = dd >> 4, hw = dd & 15;
        outc[((size_t)(b * 2048 + R) * 256 + head * 32 + d) * 16 + hw] = acc[m][n][r2] * sc;
      }
    }
}

// ---------------- context (bf16 P path): P_bf * v_t^T, scaled by inv ----------------
__global__ void __launch_bounds__(256) gemm_ctx_bf16_kernel(const unsigned short* __restrict__ pbf,
                                                            const unsigned short* __restrict__ vt,
                                                            const float* __restrict__ inv_buf,
                                                            float* __restrict__ outc) {
  __shared__ unsigned short As[4096], Bs[4096];
  f32x4 acc[4][4];
  ACC_INIT(acc);
  const int bh = blockIdx.z;
  gemm_core_async(pbf + (size_t)bh * 4194304 + (size_t)blockIdx.x * 128 * 2048, 2048,
                  vt + (size_t)bh * 1048576 + (size_t)blockIdx.y * 128 * 2048, 2048,
                  2048, As, Bs, acc);
  ctx_epilogue(acc, outc, inv_buf, bh, blockIdx.x, blockIdx.y);
}

// ---------------- context (fallback): attn fp32 * v_t^T ----------------
__global__ void __launch_bounds__(256) gemm_ctx_f32_kernel(const float* __restrict__ attn,
                                                           const unsigned short* __restrict__ vt,
                                                           float* __restrict__ outc) {
  __shared__ unsigned short As[4096], Bs[4096];
  f32x4 acc[4][4];
  ACC_INIT(acc);
  const int tid = threadIdx.x, lane = tid & 63, w = tid >> 6;
  const int wr = (w >> 1) * 64, wc = (w & 1) * 64;
  const int bh = blockIdx.z;
  const float* Ag = attn + (size_t)bh * 4194304 + (size_t)blockIdx.x * 128 * 2048;
  const unsigned short* Bg = vt + (size_t)bh * 1048576 + (size_t)blockIdx.y * 128 * 2048;
  const int r = lane >> 2, kk = (lane & 3) * 8;
  const int arow = tid >> 1, acol = (tid & 1) * 16;
  for (int k0 = 0; k0 < 2048; k0 += 32) {
#pragma unroll
    for (int i = 0; i < 2; ++i) {
      const int row0 = w * 32 + i * 16;
      async_copy16(Bg + (size_t)(row0 + r) * 2048 + k0 + kk, Bs + row0 * 32);
    }
    {
      const float* sp = Ag + (size_t)arow * 2048 + k0 + acol;
      float4 f0 = *(const float4*)(sp);
      float4 f1 = *(const float4*)(sp + 4);
      float4 f2 = *(const float4*)(sp + 8);
      float4 f3 = *(const float4*)(sp + 12);
      s16x8 h0, h1;
      h0[0] = (short)f2bf(f0.x); h0[1] = (short)f2bf(f0.y);
      h0[2] = (short)f2bf(f0.z); h0[3] = (short)f2bf(f0.w);
      h0[4] = (short)f2bf(f1.x); h0[5] = (short)f2bf(f1.y);
      h0[6] = (short)f2bf(f1.z); h0[7] = (short)f2bf(f1.w);
      h1[0] = (short)f2bf(f2.x); h1[1] = (short)f2bf(f2.y);
      h1[2] = (short)f2bf(f2.z); h1[3] = (short)f2bf(f2.w);
      h1[4] = (short)f2bf(f3.x); h1[5] = (short)f2bf(f3.y);
      h1[6] = (short)f2bf(f3.z); h1[7] = (short)f2bf(f3.w);
      *(s16x8*)(As + arow * 32 + acol) = h0;
      *(s16x8*)(As + arow * 32 + acol + 8) = h1;
    }
    __syncthreads();
    s16x8 af[4], bfv[4];
#pragma unroll
    for (int m = 0; m < 4; ++m)
      af[m] = *(const s16x8*)(As + (wr + m * 16 + (lane & 15)) * 32 + (lane >> 4) * 8);
#pragma unroll
    for (int n = 0; n < 4; ++n)
      bfv[n] = *(const s16x8*)(Bs + (wc + n * 16 + (lane & 15)) * 32 + (lane >> 4) * 8);
#pragma unroll
    for (int m = 0; m < 4; ++m)
#pragma unroll
      for (int n = 0; n < 4; ++n)
        acc[m][n] = __builtin_amdgcn_mfma_f32_16x16x32_bf16(af[m], bfv[n], acc[m][n], 0, 0, 0);
    __syncthreads();
  }
  ctx_epilogue(acc, outc, nullptr, bh, blockIdx.x, blockIdx.y);
}

extern "C" void kernel_launch(void* const* d_in, const int* in_sizes, int n_in,
                              void* d_out, int out_size, void* d_ws, size_t ws_size,
                              hipStream_t stream) {
  const float* query = (const float*)d_in[0];
  const float* key   = (const float*)d_in[1];
  const float* value = (const float*)d_in[2];
  const float* Wq    = (const float*)d_in[3];
  const float* Wk    = (const float*)d_in[4];
  const float* Wv    = (const float*)d_in[5];

  float* out_ctx  = (float*)d_out;
  float* out_attn = (float*)d_out + 16777216;

  unsigned short* X    = (unsigned short*)d_ws;
  unsigned short* q_s  = X + 16777216;
  unsigned short* k_s  = q_s + 16777216;
  unsigned short* v_t  = k_s + 16777216;   // main: [bh][dd][l]; fallback: v_s [bh][l][dd]
  unsigned short* Wbf  = v_t + 16777216;   // 196,608 shorts
  unsigned short* P_bf = Wbf + 196608;     // 67,108,864 shorts
  float* partial = (float*)(P_bf + 67108864);   // 1,048,576 floats
  float* inv_buf = partial + 1048576;           // 32,768 floats

  const bool fused = ws_size >= (size_t)273154048;

  prep_w_kernel<<<768, 256, 0, stream>>>(Wq, Wk, Wv, Wbf);

  prep_x_kernel<<<4096, 256, 0, stream>>>(query, X);
  gemm_proj_kernel<<<dim3(512, 2), 256, 0, stream>>>(X, Wbf, q_s);

  prep_x_kernel<<<4096, 256, 0, stream>>>(key, X);
  gemm_proj_kernel<<<dim3(512, 2), 256, 0, stream>>>(X, Wbf + 65536, k_s);

  if (fused) {
    prep_xv_kernel<<<4096, 256, 0, stream>>>(value, X);
    gemm_proj_vt_kernel<<<dim3(2, 512), 256, 0, stream>>>(Wbf + 131072, X, v_t);
    gemm_score_kernel<1><<<dim3(16, 16, 16), 256, 0, stream>>>(q_s, k_s, nullptr, P_bf, partial);
    norm_kernel<<<32768, 256, 0, stream>>>(P_bf, partial, out_attn, inv_buf);
    gemm_ctx_bf16_kernel<<<dim3(16, 4, 16), 256, 0, stream>>>(P_bf, v_t, inv_buf, out_ctx);
  } else {
    prep_x_kernel<<<4096, 256, 0, stream>>>(value, X);
    gemm_proj_kernel<<<dim3(512, 2), 256, 0, stream>>>(X, Wbf + 131072, v_t);  // v_s layout
    gemm_score_kernel<0><<<dim3(16, 16, 16), 256, 0, stream>>>(q_s, k_s, out_attn, nullptr, nullptr);
    softmax_kernel<<<32768, 256, 0, stream>>>(out_attn);
    transpose_v_kernel<<<dim3(32, 8, 16), 256, 0, stream>>>(v_t, X);           // X becomes v_t
    gemm_ctx_f32_kernel<<<dim3(16, 4, 16), 256, 0, stream>>>(out_attn, X, out_ctx);
  }
}